// Round 4
// baseline (16274.261 us; speedup 1.0000x reference)
//
#include <hip/hip_runtime.h>
#include <hip/hip_fp16.h>
#include <stdint.h>

// ---------------------------------------------------------------------------
// SequentialEMGPoseLSTM: 2-layer LSTM (H=256, B=64, T=4096) + LeakyReLU+Linear
//
// R6 changes vs R5 (post-mortem: VGPR_Count=128 even with NO MFMA -> the
// backend budgets 128 arch VGPRs at this occupancy no matter what; and the
// GEMM role was co-critical: 4096 blocks x 153KB static LDS = 1 block/CU =
// 32 serialized rounds on the 128 free CUs, which is the persistent ~4ms
// gap between sum-of-dispatches and the timed total):
//  - Recurrent role redesigned for a 128-VGPR budget: 1024 threads, 8
//    k-slices of 32; register weights = 6 rows x 16 u32 = 96 VGPRs; bias
//    folded into xw0/xw1 at the producers; rolling 1-uint4 h reads; DPP
//    8-lane reduce (quad_perm x2 + row_half_mirror). No AGPR shuffling by
//    construction.
//  - GEMM role: exactly 128 fat blocks (1 per free CU). Each stages a
//    256-row A-strip into the proven 264-stride LDS layout once, then 16
//    passes of 64 N-cols with wave-broadcast global B reads (L2-resident).
//    Conflict-free, fully concurrent with the recurrent role.
//  - Grid = 256 blocks = 256 CUs exactly.
// ---------------------------------------------------------------------------

#define T_SEQ 4096
#define NB    64
#define HID   256
#define G4    1024
#define INCH  16
#define OC    20
#define THREADS 1024

typedef _Float16 h2v __attribute__((ext_vector_type(2)));

__device__ __forceinline__ float fdot2(uint32_t a, uint32_t b, float c) {
  return __builtin_amdgcn_fdot2(__builtin_bit_cast(h2v, a),
                                __builtin_bit_cast(h2v, b), c, false);
}
__device__ __forceinline__ float sigf(float x) {
  x = fminf(fmaxf(x, -30.f), 30.f);
  return 1.f / (1.f + __expf(-x));
}
__device__ __forceinline__ float tanhf_fast(float x) {
  x = fminf(fmaxf(x, -15.f), 15.f);
  float e = __expf(-2.f * x);
  return (1.f - e) / (1.f + e);
}
// Sum across 8 lanes (lane bits 0-2): quad_perm(1,0,3,2)=0xB1,
// quad_perm(2,3,0,1)=0x4E, then row_half_mirror=0x141 pairs the two quads.
__device__ __forceinline__ float oct_sum(float a) {
  a += __int_as_float(
      __builtin_amdgcn_update_dpp(0, __float_as_int(a), 0xB1, 0xF, 0xF, true));
  a += __int_as_float(
      __builtin_amdgcn_update_dpp(0, __float_as_int(a), 0x4E, 0xF, 0xF, true));
  a += __int_as_float(
      __builtin_amdgcn_update_dpp(0, __float_as_int(a), 0x141, 0xF, 0xF, true));
  return a;
}
__device__ __forceinline__ uint32_t pkh2(float a, float b) {
  return (uint32_t)__half_as_ushort(__float2half(a)) |
         ((uint32_t)__half_as_ushort(__float2half(b)) << 16);
}

#define PIN(x) asm volatile("" : "+v"(x))

// LDS layout:
//  w   : 256 rows x 264 halves (stride 264 -> 4-bank step per row; 8-phase
//        minimum for row-strided b128 reads). Rec: Whh rows 768..1023.
//        GEMM: the 256-row A strip.
//  hbuf: 2 x (8 slices x 40 halves). Slice s at bank 20s%32 -> all distinct.
//  u.xb: layer0 packed x pairs. u.h1: head weights + leaky buffer.
struct SmemR {
  __half w[256 * 264];        // 135168 B
  uint32_t hbuf[2][160];      // 1280 B
  union {
    uint32_t xb[512 * 8];     // 16384 B (Tc<=512)
    struct {
      __half abuf[2][320];
      __half whd[20 * 264];
      float  bh[20];
    } h1;
  } u;
};

struct Params {
  const float* x;
  const __half *wh0, *wh1, *wi0, *wi1, *whd;
  const float  *bs0, *bs1, *bhd;
  float *h0s, *c0s, *h1s, *c1s;
  __half* h1w; const __half* h1r;
  __half* xw1w; const __half* xw1r;  // layer1 input-contrib (GEMM writes, +bias)
  __half* xw0w; const __half* xw0r;  // layer0 input-contrib (prologue, +bias)
  float* y;
  int L, Tc, nch;
};

// ---------------------------------------------------------------------------
// xw0[(tt*NB+b)*G4 + g] = (Wih0 row g).x_t + bs0[g]  (f16). 1024 threads,
// one gate row per thread. x staged packed in S.u.xb (broadcast reads).
// ---------------------------------------------------------------------------
__device__ void compute_xw0(SmemR& S, int cc, const Params& P, int b,
                            __half* out) {
  const int tid = threadIdx.x;
  const int Tc  = P.Tc;
  const int t0  = cc * Tc;
  for (int i = tid; i < Tc * 8; i += THREADS) {
    int dp = i / Tc, tt = i - dp * Tc;
    S.u.xb[tt * 8 + dp] =
        pkh2(P.x[(b * INCH + 2 * dp) * T_SEQ + t0 + tt],
             P.x[(b * INCH + 2 * dp + 1) * T_SEQ + t0 + tt]);
  }
  __syncthreads();
  uint32_t w0[8];
  {
    const uint4* p0 = (const uint4*)(P.wi0 + tid * INCH);
    uint4 a0 = p0[0], a1 = p0[1];
    w0[0] = a0.x; w0[1] = a0.y; w0[2] = a0.z; w0[3] = a0.w;
    w0[4] = a1.x; w0[5] = a1.y; w0[6] = a1.z; w0[7] = a1.w;
  }
  const float bA = P.bs0[tid];
  for (int tt = 0; tt < Tc; ++tt) {
    const uint4* xp = (const uint4*)&S.u.xb[tt * 8];
    uint4 v0 = xp[0], v1 = xp[1];
    float a0 = bA;
    a0 = fdot2(w0[0], v0.x, a0); a0 = fdot2(w0[1], v0.y, a0);
    a0 = fdot2(w0[2], v0.z, a0); a0 = fdot2(w0[3], v0.w, a0);
    a0 = fdot2(w0[4], v1.x, a0); a0 = fdot2(w0[5], v1.y, a0);
    a0 = fdot2(w0[6], v1.z, a0); a0 = fdot2(w0[7], v1.w, a0);
    out[(size_t)(tt * NB + b) * G4 + tid] = __float2half(a0);
  }
  __syncthreads();  // xb reusable; stores drained by the barrier's vmcnt(0)
}

// ---------------------------------------------------------------------------
// Recurrent role: one block == one batch chain. 1024 threads.
// slice = tid&7 covers k in [32*slice, 32*slice+32); rg = tid>>3 (0..127).
// Thread handles gate rows r = rg + 128*j, j=0..7 (j<6 reg, j>=6 LDS).
// j even -> channel rg, j odd -> channel rg+128, gate j>>1.
// Owners: slice0 -> channel rg, slice1 -> channel rg+128.
// ---------------------------------------------------------------------------
template <int LAYER>
__device__ void role_rec(SmemR& S, int ch, const Params& P, int b) {
  if (ch < 0 || ch >= P.nch) return;
  const int tid   = threadIdx.x;
  const int slice = tid & 7;
  const int rg    = tid >> 3;
  const int Tc    = P.Tc;
  const __half* whh = (LAYER == 0) ? P.wh0 : P.wh1;

  // Stage LDS-resident weight rows 768..1023 into padded layout.
  for (int i = tid; i < 8192; i += THREADS) {
    int R = i >> 5, oct = i & 31;
    *(uint4*)&S.w[R * 264 + oct * 8] =
        *((const uint4*)(whh + (768 + R) * 256) + oct);
  }
  const int t0 = ch * Tc;
  if (LAYER == 0) {
    if (ch == 0) compute_xw0(S, 0, P, b, (__half*)P.xw0r);
    if (ch + 1 < P.nch) compute_xw0(S, ch + 1, P, b, P.xw0w);
  } else {
    for (int i = tid; i < OC * 256; i += THREADS) {
      int o = i >> 8, k = i & 255;
      S.u.h1.whd[o * 264 + k] = P.whd[i];
    }
    if (tid < OC) S.u.h1.bh[tid] = P.bhd[tid];
  }

  // Register-resident weights: rows j=0..5, 32 halves each (16 packed u32).
  uint32_t wr[6][16];
#pragma unroll
  for (int j = 0; j < 6; j++) {
    const uint4* p = (const uint4*)(whh + (rg + 128 * j) * 256 + slice * 32);
#pragma unroll
    for (int q = 0; q < 4; q++) {
      uint4 v = p[q];
      wr[j][4 * q] = v.x; wr[j][4 * q + 1] = v.y;
      wr[j][4 * q + 2] = v.z; wr[j][4 * q + 3] = v.w;
    }
  }
#pragma unroll
  for (int j = 0; j < 6; j++)
#pragma unroll
    for (int q = 0; q < 16; q++) PIN(wr[j][q]);

  // Owner state: slice0 -> channel rg; slice1 -> channel rg+128 (fp32 h,c).
  const bool own = (slice < 2);
  const int chn = rg + (slice << 7);  // valid for owners (slice in {0,1})
  float* hs = (LAYER == 0) ? P.h0s : P.h1s;
  float* cs = (LAYER == 0) ? P.c0s : P.c1s;
  float hO = 0.f, cO = 0.f;
  if (own) {
    if (ch != 0) { hO = hs[b * 256 + chn]; cO = cs[b * 256 + chn]; }
    ((__half*)S.hbuf[0])[(chn >> 5) * 40 + (chn & 31)] = __float2half(hO);
  }
  const __half* xp = nullptr;
  if (own) xp = ((LAYER == 0) ? P.xw0r : P.xw1r) + (size_t)b * G4 + chn;
  __syncthreads();

  const __half* hbA = (const __half*)S.hbuf[0] + slice * 40;
  const __half* hbB = (const __half*)S.hbuf[1] + slice * 40;
  const uint4* w6 = (const uint4*)&S.w[rg * 264 + slice * 32];
  const uint4* w7 = (const uint4*)&S.w[(128 + rg) * 264 + slice * 32];
  __half hprev = __float2half(0.f);

  for (int tt = 0; tt < Tc; ++tt) {
    // ---- post-barrier zone: global ops retire under this step's compute.
    if (LAYER == 0 && own && tt > 0)
      P.h1w[(size_t)((tt - 1) * NB + b) * 256 + chn] = hprev;
    float xwv[4] = {0.f, 0.f, 0.f, 0.f};
    if (own) {
      const __half* q = xp + (size_t)tt * (NB * G4);
      xwv[0] = __half2float(q[0]);
      xwv[1] = __half2float(q[256]);
      xwv[2] = __half2float(q[512]);
      xwv[3] = __half2float(q[768]);
    }

    const uint4* hp = (const uint4*)((tt & 1) ? hbB : hbA);
    float acc[8];
#pragma unroll
    for (int j = 0; j < 8; j++) acc[j] = 0.f;

    // 4 sub-blocks of 8 halves: rolling 1-uint4 h keeps live regs minimal.
#pragma unroll
    for (int sb = 0; sb < 4; ++sb) {
      uint4 hv = hp[sb];
#pragma unroll
      for (int j = 0; j < 6; ++j) {
        float a = acc[j];
        a = fdot2(wr[j][4 * sb + 0], hv.x, a);
        a = fdot2(wr[j][4 * sb + 1], hv.y, a);
        a = fdot2(wr[j][4 * sb + 2], hv.z, a);
        a = fdot2(wr[j][4 * sb + 3], hv.w, a);
        acc[j] = a;
      }
      {
        uint4 wv = w6[sb];
        float a = acc[6];
        a = fdot2(wv.x, hv.x, a); a = fdot2(wv.y, hv.y, a);
        a = fdot2(wv.z, hv.z, a); a = fdot2(wv.w, hv.w, a);
        acc[6] = a;
      }
      {
        uint4 wv = w7[sb];
        float a = acc[7];
        a = fdot2(wv.x, hv.x, a); a = fdot2(wv.y, hv.y, a);
        a = fdot2(wv.z, hv.z, a); a = fdot2(wv.w, hv.w, a);
        acc[7] = a;
      }
    }
    // Reduce across the 8 slices on the VALU pipe (DPP).
#pragma unroll
    for (int j = 0; j < 8; j++) acc[j] = oct_sum(acc[j]);

    if (own) {
      const int o = slice;  // 0 -> channel rg (even j), 1 -> rg+128 (odd j)
      float gi = acc[0 + o] + xwv[0];
      float gf = acc[2 + o] + xwv[1];
      float gg = acc[4 + o] + xwv[2];
      float go = acc[6 + o] + xwv[3];
      float iv = sigf(gi), fv = sigf(gf);
      float gv = tanhf_fast(gg), ov = sigf(go);
      cO = fv * cO + iv * gv;
      hO = ov * tanhf_fast(cO);
      __half h16 = __float2half(hO);
      ((__half*)S.hbuf[(tt + 1) & 1])[(chn >> 5) * 40 + (chn & 31)] = h16;
      if (LAYER == 0) {
        hprev = h16;  // stored at top of next iteration (post-barrier)
      } else {
        float av = hO > 0.f ? hO : 0.01f * hO;
        S.u.h1.abuf[tt & 1][(chn >> 5) * 40 + (chn & 31)] = __float2half(av);
      }
    }
    __syncthreads();

    // Head (layer1): 20 outputs x 8 lanes x 32 k. Reads abuf[tt&1] written
    // before the barrier; its next overwrite is 2 steps away and gated by
    // the intervening barrier.
    if (LAYER == 1 && tid < OC * 8) {
      int o = tid >> 3, ks = tid & 7;
      const uint4* wp = (const uint4*)&S.u.h1.whd[o * 264 + ks * 32];
      const uint4* ap = (const uint4*)&S.u.h1.abuf[tt & 1][ks * 40];
      float a = 0.f;
#pragma unroll
      for (int q = 0; q < 4; q++) {
        uint4 w4 = wp[q];
        uint4 a4 = ap[q];
        a = fdot2(w4.x, a4.x, a);
        a = fdot2(w4.y, a4.y, a);
        a = fdot2(w4.z, a4.z, a);
        a = fdot2(w4.w, a4.w, a);
      }
      a += __shfl_xor(a, 1);
      a += __shfl_xor(a, 2);
      a += __shfl_xor(a, 4);
      if (ks == 0) P.y[(b * OC + o) * T_SEQ + t0 + tt] = a + S.u.h1.bh[o];
    }
  }
  if (own) {
    if (LAYER == 0)
      P.h1w[(size_t)((Tc - 1) * NB + b) * 256 + chn] = hprev;
    hs[b * 256 + chn] = hO;
    cs[b * 256 + chn] = cO;
  }
}

// ---------------------------------------------------------------------------
// GEMM role (VALU fdot2): xw1[tb,g] = sum_k h1[tb,k]*Wih1[g,k] + bs1[g].
// 128 blocks, 1 per free CU. Each block: 256-row A strip staged once into
// S.w ([256][264] -> conflict-free row-strided reads), 16 passes of 64 g-cols
// with wave-broadcast global B reads (wi1 is L2-resident, shared by all).
// Thread: tm=tid>>4 -> rows {tm+64r}, tn=tid&15 -> cols {np*64+tn*4+c}.
// Per wave: A-reads have 4 distinct addrs (16-way broadcast), B-reads 64.
// ---------------------------------------------------------------------------
__device__ void role_gemm(SmemR& S, int chG, const Params& P) {
  if (chG < 0 || chG >= P.nch) return;
  const int strip  = blockIdx.x - 128;
  const int nstrip = (P.Tc * NB) >> 8;
  if (strip >= nstrip) return;
  const int tb0 = strip * 256;
  const int tid = threadIdx.x;

  for (int i = tid; i < 8192; i += THREADS) {
    int R = i >> 5, oct = i & 31;
    *(uint4*)&S.w[R * 264 + oct * 8] =
        *((const uint4*)(P.h1r + (size_t)(tb0 + R) * 256) + oct);
  }
  __syncthreads();

  const int tm = tid >> 4;  // 0..63
  const int tn = tid & 15;
  for (int np = 0; np < 16; ++np) {
    const int g0 = np * 64 + tn * 4;
    float bsv0 = P.bs1[g0], bsv1 = P.bs1[g0 + 1];
    float bsv2 = P.bs1[g0 + 2], bsv3 = P.bs1[g0 + 3];
    const __half* bp = P.wi1 + (size_t)g0 * 256;
    float acc[4][4] = {};
#pragma unroll 2
    for (int kq = 0; kq < 32; ++kq) {
      uint4 av[4], bv[4];
#pragma unroll
      for (int r = 0; r < 4; ++r)
        av[r] = *(const uint4*)&S.w[(tm + 64 * r) * 264 + kq * 8];
#pragma unroll
      for (int c = 0; c < 4; ++c)
        bv[c] = *(const uint4*)(bp + (size_t)c * 256 + kq * 8);
#pragma unroll
      for (int r = 0; r < 4; ++r)
#pragma unroll
        for (int c = 0; c < 4; ++c) {
          float a = acc[r][c];
          a = fdot2(av[r].x, bv[c].x, a);
          a = fdot2(av[r].y, bv[c].y, a);
          a = fdot2(av[r].z, bv[c].z, a);
          a = fdot2(av[r].w, bv[c].w, a);
          acc[r][c] = a;
        }
    }
#pragma unroll
    for (int r = 0; r < 4; ++r) {
      uint32_t* o =
          (uint32_t*)(P.xw1w + (size_t)(tb0 + tm + 64 * r) * G4 + g0);
      o[0] = pkh2(acc[r][0] + bsv0, acc[r][1] + bsv1);
      o[1] = pkh2(acc[r][2] + bsv2, acc[r][3] + bsv3);
    }
  }
}

__global__ __launch_bounds__(THREADS, 4)
void fused_kernel(Params P) {
  __shared__ SmemR S;
  int bid = blockIdx.x;
  if (bid < 64)        role_rec<0>(S, P.L, P, bid);
  else if (bid < 128)  role_rec<1>(S, P.L - 2, P, bid - 64);
  else                 role_gemm(S, P.L - 1, P);
}

// ---------------------------------------------------------------------------
__global__ void prep_kernel(const float* Wih0, const float* Whh0,
                            const float* bih0, const float* bhh0,
                            const float* Wih1, const float* Whh1,
                            const float* bih1, const float* bhh1,
                            const float* Whead, const float* bhead,
                            __half* wh0, __half* wh1, __half* wi1, __half* wi0,
                            __half* whd, float* bs0, float* bs1, float* bhd) {
  int i = blockIdx.x * blockDim.x + threadIdx.x;
  if (i < G4 * HID) {
    wh0[i] = __float2half(Whh0[i]);
    wh1[i] = __float2half(Whh1[i]);
    wi1[i] = __float2half(Wih1[i]);
  }
  if (i < G4 * INCH) wi0[i] = __float2half(Wih0[i]);
  if (i < OC * HID)  whd[i] = __float2half(Whead[i]);
  if (i < G4) { bs0[i] = bih0[i] + bhh0[i]; bs1[i] = bih1[i] + bhh1[i]; }
  if (i < OC) bhd[i] = bhead[i];
}

// ---------------------------------------------------------------------------
extern "C" void kernel_launch(void* const* d_in, const int* in_sizes, int n_in,
                              void* d_out, int out_size, void* d_ws, size_t ws_size,
                              hipStream_t stream) {
  const float* x     = (const float*)d_in[0];
  const float* Wih0  = (const float*)d_in[1];
  const float* Whh0  = (const float*)d_in[2];
  const float* bih0  = (const float*)d_in[3];
  const float* bhh0  = (const float*)d_in[4];
  const float* Wih1  = (const float*)d_in[5];
  const float* Whh1  = (const float*)d_in[6];
  const float* bih1  = (const float*)d_in[7];
  const float* bhh1  = (const float*)d_in[8];
  const float* Whead = (const float*)d_in[9];
  const float* bhead = (const float*)d_in[10];
  float* y = (float*)d_out;

  char* ws = (char*)d_ws;
  size_t cur = 0;
  auto alloc = [&](size_t sz) -> char* {
    char* p = ws + cur;
    cur = (cur + sz + 255) & ~(size_t)255;
    return p;
  };
  __half* wh0 = (__half*)alloc(G4 * HID * 2);
  __half* wh1 = (__half*)alloc(G4 * HID * 2);
  __half* wi1 = (__half*)alloc(G4 * HID * 2);
  __half* wi0 = (__half*)alloc(G4 * INCH * 2);
  __half* whd = (__half*)alloc(OC * HID * 2);
  float* bs0 = (float*)alloc(G4 * 4);
  float* bs1 = (float*)alloc(G4 * 4);
  float* bhd = (float*)alloc(OC * 4);
  float* h0s = (float*)alloc(NB * HID * 4);
  float* c0s = (float*)alloc(NB * HID * 4);
  float* h1s = (float*)alloc(NB * HID * 4);
  float* c1s = (float*)alloc(NB * HID * 4);
  size_t fixed = cur;

  int Tc = 512;
  while (Tc > 64) {
    size_t need = fixed + 2 * ((size_t)Tc * NB * HID * 2 + 512) +
                  4 * ((size_t)Tc * NB * G4 * 2 + 512);
    if (need <= ws_size) break;
    Tc >>= 1;
  }
  __half* h1buf[2];
  __half* xw1buf[2];
  __half* xw0buf[2];
  h1buf[0]  = (__half*)alloc((size_t)Tc * NB * HID * 2);
  h1buf[1]  = (__half*)alloc((size_t)Tc * NB * HID * 2);
  xw1buf[0] = (__half*)alloc((size_t)Tc * NB * G4 * 2);
  xw1buf[1] = (__half*)alloc((size_t)Tc * NB * G4 * 2);
  xw0buf[0] = (__half*)alloc((size_t)Tc * NB * G4 * 2);
  xw0buf[1] = (__half*)alloc((size_t)Tc * NB * G4 * 2);

  const int nch = T_SEQ / Tc;

  prep_kernel<<<(G4 * HID + 255) / 256, 256, 0, stream>>>(
      Wih0, Whh0, bih0, bhh0, Wih1, Whh1, bih1, bhh1, Whead, bhead,
      wh0, wh1, wi1, wi0, whd, bs0, bs1, bhd);

  for (int L = 0; L < nch + 2; ++L) {
    Params P;
    P.x = x;
    P.wh0 = wh0; P.wh1 = wh1; P.wi0 = wi0; P.wi1 = wi1; P.whd = whd;
    P.bs0 = bs0; P.bs1 = bs1; P.bhd = bhd;
    P.h0s = h0s; P.c0s = c0s; P.h1s = h1s; P.c1s = c1s;
    P.h1w = h1buf[L & 1];
    P.h1r = h1buf[(L + 1) & 1];
    P.xw1w = xw1buf[(L + 1) & 1];
    P.xw1r = xw1buf[L & 1];
    P.xw0w = xw0buf[(L + 1) & 1];
    P.xw0r = xw0buf[L & 1];
    P.y = y;
    P.L = L; P.Tc = Tc; P.nch = nch;
    fused_kernel<<<256, THREADS, 0, stream>>>(P);
  }
}

// Round 5
// 13060.979 us; speedup vs baseline: 1.2460x; 1.2460x over previous
//
#include <hip/hip_runtime.h>
#include <hip/hip_fp16.h>
#include <stdint.h>

// ---------------------------------------------------------------------------
// SequentialEMGPoseLSTM: 2-layer LSTM (H=256, B=64, T=4096) + LeakyReLU+Linear
//
// R7 changes vs R6 (post-mortem: allocator always grants HALF the pool as
// arch VGPRs (128@512thr, 64@1024thr) -> stop fighting, pin 4 weight rows
// into AGPRs explicitly; and dispatch-0 VALUBusy=5.5% shows the step is
// ~90% stall -> the per-step __syncthreads emits s_waitcnt vmcnt(0) which
// drains the in-flight h1w stores / xw loads EVERY step (~600-900 cyc)):
//  - Per-step barrier is now raw `s_waitcnt lgkmcnt(0); s_barrier` (LDS
//    ordering only). Global ops float across steps (h1w consumed next
//    dispatch; xw buffer is read-only; y is final output).
//  - Rec blocks: 256 threads, 1 wave/SIMD (waves_per_eu(1,1) -> 256 arch +
//    256 acc budget). slice=tid&1 (128 halves), rg=tid>>1; every thread
//    owns exactly one channel -> no idle lanes in the tail; reduce = 1 DPP.
//    Weights: j=0,1 pinned "+v" (128 VGPR); j=2..5 pinned "+a" (256 AGPR);
//    j=6,7 from LDS. Fully resident by construction.
//  - xw prefetched one step ahead (R3's scheme, both layers).
//  - GEMM role loops 128-row strips so it covers any Tc with 128 blocks,
//    concurrent with the rec role.
// ---------------------------------------------------------------------------

#define T_SEQ 4096
#define NB    64
#define HID   256
#define G4    1024
#define INCH  16
#define OC    20
#define THREADS 256

typedef _Float16 h2v __attribute__((ext_vector_type(2)));

__device__ __forceinline__ float fdot2(uint32_t a, uint32_t b, float c) {
  return __builtin_amdgcn_fdot2(__builtin_bit_cast(h2v, a),
                                __builtin_bit_cast(h2v, b), c, false);
}
__device__ __forceinline__ float sigf(float x) {
  x = fminf(fmaxf(x, -30.f), 30.f);
  return 1.f / (1.f + __expf(-x));
}
__device__ __forceinline__ float tanhf_fast(float x) {
  x = fminf(fmaxf(x, -15.f), 15.f);
  float e = __expf(-2.f * x);
  return (1.f - e) / (1.f + e);
}
// Sum lane with lane^1 (slice partner): quad_perm(1,0,3,2) = 0xB1.
__device__ __forceinline__ float pair_sum(float a) {
  a += __int_as_float(
      __builtin_amdgcn_update_dpp(0, __float_as_int(a), 0xB1, 0xF, 0xF, true));
  return a;
}
__device__ __forceinline__ uint32_t pkh2(float a, float b) {
  return (uint32_t)__half_as_ushort(__float2half(a)) |
         ((uint32_t)__half_as_ushort(__float2half(b)) << 16);
}

#define PIN_V(x) asm volatile("" : "+v"(x))
#define PIN_A(x) asm volatile("" : "+a"(x))
// LDS-only barrier: no vmcnt drain (global ops deliberately float across
// steps). "memory" clobber stops the compiler moving LDS ops across it.
#define STEP_BARRIER() asm volatile("s_waitcnt lgkmcnt(0)\n\ts_barrier" ::: "memory")

// LDS layout (all hot rows 16B-aligned):
//  w   : 256 rows x 264 halves (rows 768..1023 of Whh / GEMM A-strip).
//        Row stride 528B -> 4-bank step -> balanced 8-phase b128 reads.
//  hbuf: 2 x 256 halves, h state double buffer. Writes: 2 lanes/bank (free).
//        Reads: 2 distinct b128 addrs/wave, 32-way broadcast (free).
struct SmemR {
  __half w[256 * 264];        // 135168 B
  __half hbuf[2][256];        // 1024 B
  union {
    uint32_t xb[512 * 8];     // layer0 prologue: packed x pairs (Tc<=512)
    struct {
      __half abuf[2][256];    // layer1: leaky(h2) double buffer
      __half whd[20 * 264];   // head weights, padded rows
      float  bh[20];
    } h1;
  } u;
};

struct Params {
  const float* x;
  const __half *wh0, *wh1, *wi0, *wi1, *whd;
  const float  *bs0, *bs1, *bhd;
  float *h0s, *c0s, *h1s, *c1s;
  __half* h1w; const __half* h1r;
  __half* xw1w; const __half* xw1r;  // layer1 input-contrib (GEMM writes, +bias)
  __half* xw0w; const __half* xw0r;  // layer0 input-contrib (prologue, +bias)
  float* y;
  int L, Tc, nch;
};

// ---------------------------------------------------------------------------
// xw0[(tt*NB+b)*G4 + g] = (Wih0 row g).x_t + bs0[g]  (f16). 256 threads,
// 4 gate rows per thread (tid + 256r). x staged packed in S.u.xb.
// ---------------------------------------------------------------------------
__device__ void compute_xw0(SmemR& S, int cc, const Params& P, int b,
                            __half* out) {
  const int tid = threadIdx.x;
  const int Tc  = P.Tc;
  const int t0  = cc * Tc;
  for (int dp = 0; dp < 8; ++dp)
    for (int tt = tid; tt < Tc; tt += THREADS)
      S.u.xb[tt * 8 + dp] =
          pkh2(P.x[(b * INCH + 2 * dp) * T_SEQ + t0 + tt],
               P.x[(b * INCH + 2 * dp + 1) * T_SEQ + t0 + tt]);
  __syncthreads();
  uint32_t w[4][8];
  float bb[4];
#pragma unroll
  for (int r = 0; r < 4; ++r) {
    const uint4* p = (const uint4*)(P.wi0 + (tid + 256 * r) * INCH);
    uint4 a0 = p[0], a1 = p[1];
    w[r][0] = a0.x; w[r][1] = a0.y; w[r][2] = a0.z; w[r][3] = a0.w;
    w[r][4] = a1.x; w[r][5] = a1.y; w[r][6] = a1.z; w[r][7] = a1.w;
    bb[r] = P.bs0[tid + 256 * r];
  }
  for (int tt = 0; tt < Tc; ++tt) {
    const uint4* xp = (const uint4*)&S.u.xb[tt * 8];
    uint4 v0 = xp[0], v1 = xp[1];
    __half* o = out + (size_t)(tt * NB + b) * G4;
#pragma unroll
    for (int r = 0; r < 4; ++r) {
      float a = bb[r];
      a = fdot2(w[r][0], v0.x, a); a = fdot2(w[r][1], v0.y, a);
      a = fdot2(w[r][2], v0.z, a); a = fdot2(w[r][3], v0.w, a);
      a = fdot2(w[r][4], v1.x, a); a = fdot2(w[r][5], v1.y, a);
      a = fdot2(w[r][6], v1.z, a); a = fdot2(w[r][7], v1.w, a);
      o[tid + 256 * r] = __float2half(a);
    }
  }
  __syncthreads();  // xb reusable; stores drained by barrier's vmcnt(0)
}

// ---------------------------------------------------------------------------
// Recurrent role: one block == one batch chain. 256 threads (4 waves,
// 1 wave/SIMD). slice = tid&1 covers k in [128*slice, 128*slice+128);
// rg = tid>>1 (0..127). Thread handles gate rows r = rg + 128*j, j=0..7
// (j=0,1 VGPR; j=2..5 AGPR; j=6,7 LDS). j even -> channel rg, j odd ->
// channel rg+128, gate j>>1. Thread owns channel chn = rg + (slice<<7).
// ---------------------------------------------------------------------------
template <int LAYER>
__device__ void role_rec(SmemR& S, int ch, const Params& P, int b) {
  if (ch < 0 || ch >= P.nch) return;
  const int tid   = threadIdx.x;
  const int slice = tid & 1;
  const int rg    = tid >> 1;
  const int Tc    = P.Tc;
  const __half* whh = (LAYER == 0) ? P.wh0 : P.wh1;

  // Stage LDS-resident weight rows 768..1023 (gate o) into padded layout.
  for (int i = tid; i < 8192; i += THREADS) {
    int R = i >> 5, oct = i & 31;
    *(uint4*)&S.w[R * 264 + oct * 8] =
        *((const uint4*)(whh + (768 + R) * 256) + oct);
  }
  const int t0 = ch * Tc;
  if (LAYER == 0) {
    if (ch == 0) compute_xw0(S, 0, P, b, (__half*)P.xw0r);
    if (ch + 1 < P.nch) compute_xw0(S, ch + 1, P, b, P.xw0w);
  } else {
    for (int i = tid; i < OC * 256; i += THREADS) {
      int o = i >> 8, k = i & 255;
      S.u.h1.whd[o * 264 + k] = P.whd[i];
    }
    if (tid < OC) S.u.h1.bh[tid] = P.bhd[tid];
  }

  // Register-resident weights: row-slice = 128 halves = 64 u32 per row.
  // j=0,1 -> arch VGPRs (128); j=2..5 -> AGPRs (256, the acc cap).
  uint32_t wv[2][64], wa[4][64];
#pragma unroll
  for (int j = 0; j < 2; ++j) {
    const uint4* p = (const uint4*)(whh + (rg + 128 * j) * 256 + slice * 128);
#pragma unroll
    for (int q = 0; q < 16; ++q) {
      uint4 v = p[q];
      wv[j][4 * q] = v.x; wv[j][4 * q + 1] = v.y;
      wv[j][4 * q + 2] = v.z; wv[j][4 * q + 3] = v.w;
    }
  }
#pragma unroll
  for (int j = 0; j < 4; ++j) {
    const uint4* p =
        (const uint4*)(whh + (rg + 128 * (2 + j)) * 256 + slice * 128);
#pragma unroll
    for (int q = 0; q < 16; ++q) {
      uint4 v = p[q];
      wa[j][4 * q] = v.x; wa[j][4 * q + 1] = v.y;
      wa[j][4 * q + 2] = v.z; wa[j][4 * q + 3] = v.w;
    }
  }
#pragma unroll
  for (int j = 0; j < 2; ++j)
#pragma unroll
    for (int q = 0; q < 64; ++q) PIN_V(wv[j][q]);
#pragma unroll
  for (int j = 0; j < 4; ++j)
#pragma unroll
    for (int q = 0; q < 64; ++q) PIN_A(wa[j][q]);

  // Owner state: every thread owns one channel.
  const int chn = rg + (slice << 7);
  float* hs = (LAYER == 0) ? P.h0s : P.h1s;
  float* cs = (LAYER == 0) ? P.c0s : P.c1s;
  float hO = 0.f, cO = 0.f;
  if (ch != 0) { hO = hs[b * 256 + chn]; cO = cs[b * 256 + chn]; }
  S.hbuf[0][chn] = __float2half(hO);
  const __half* xp =
      ((LAYER == 0) ? P.xw0r : P.xw1r) + (size_t)b * G4 + chn;
  __syncthreads();

  // xw for tt=0 (synchronous); thereafter prefetched one step ahead.
  float xwc0, xwc1, xwc2, xwc3;
  { const __half* q = xp;
    xwc0 = __half2float(q[0]);   xwc1 = __half2float(q[256]);
    xwc2 = __half2float(q[512]); xwc3 = __half2float(q[768]); }
  __half hprev = __float2half(0.f);

  for (int tt = 0; tt < Tc; ++tt) {
    // Post-barrier zone: these global ops float across steps (no vmcnt
    // drain at the step barrier).
    if (LAYER == 0 && tt > 0)
      P.h1w[(size_t)((tt - 1) * NB + b) * 256 + chn] = hprev;
    __half xn0, xn1, xn2, xn3;
    { int tn = (tt + 1 < Tc) ? tt + 1 : tt;
      const __half* q = xp + (size_t)tn * (NB * G4);
      xn0 = q[0]; xn1 = q[256]; xn2 = q[512]; xn3 = q[768]; }

    const uint4* hp = (const uint4*)(&S.hbuf[tt & 1][slice * 128]);
    const uint4* w6 = (const uint4*)&S.w[rg * 264 + slice * 128];
    const uint4* w7 = (const uint4*)&S.w[(128 + rg) * 264 + slice * 128];
    float acc[8];
#pragma unroll
    for (int j = 0; j < 8; ++j) acc[j] = 0.f;

    // 8 sub-blocks of 16 halves (8 u32): rolling hh, static indexing only.
#pragma unroll
    for (int sb = 0; sb < 8; ++sb) {
      uint32_t hh[8];
      { uint4 a = hp[2 * sb], c = hp[2 * sb + 1];
        hh[0] = a.x; hh[1] = a.y; hh[2] = a.z; hh[3] = a.w;
        hh[4] = c.x; hh[5] = c.y; hh[6] = c.z; hh[7] = c.w; }
#pragma unroll
      for (int j = 0; j < 2; ++j) {
        float a = acc[j];
#pragma unroll
        for (int q = 0; q < 8; ++q) a = fdot2(wv[j][8 * sb + q], hh[q], a);
        acc[j] = a;
      }
#pragma unroll
      for (int j = 0; j < 4; ++j) {
        float a = acc[2 + j];
#pragma unroll
        for (int q = 0; q < 8; ++q) a = fdot2(wa[j][8 * sb + q], hh[q], a);
        acc[2 + j] = a;
      }
      { uint4 wA = w6[2 * sb], wB = w6[2 * sb + 1];
        float a = acc[6];
        a = fdot2(wA.x, hh[0], a); a = fdot2(wA.y, hh[1], a);
        a = fdot2(wA.z, hh[2], a); a = fdot2(wA.w, hh[3], a);
        a = fdot2(wB.x, hh[4], a); a = fdot2(wB.y, hh[5], a);
        a = fdot2(wB.z, hh[6], a); a = fdot2(wB.w, hh[7], a);
        acc[6] = a; }
      { uint4 wA = w7[2 * sb], wB = w7[2 * sb + 1];
        float a = acc[7];
        a = fdot2(wA.x, hh[0], a); a = fdot2(wA.y, hh[1], a);
        a = fdot2(wA.z, hh[2], a); a = fdot2(wA.w, hh[3], a);
        a = fdot2(wB.x, hh[4], a); a = fdot2(wB.y, hh[5], a);
        a = fdot2(wB.z, hh[6], a); a = fdot2(wB.w, hh[7], a);
        acc[7] = a; }
    }
    // Reduce lane pairs (slice 0 <-> 1) on the VALU pipe.
#pragma unroll
    for (int j = 0; j < 8; ++j) acc[j] = pair_sum(acc[j]);

    // Tail: ALL lanes productive (each owns one channel). Static selects.
    float gi = slice ? acc[1] : acc[0];
    float gf = slice ? acc[3] : acc[2];
    float gg = slice ? acc[5] : acc[4];
    float go = slice ? acc[7] : acc[6];
    gi += xwc0; gf += xwc1; gg += xwc2; go += xwc3;
    float iv = sigf(gi), fv = sigf(gf);
    float gv = tanhf_fast(gg), ov = sigf(go);
    cO = fv * cO + iv * gv;
    hO = ov * tanhf_fast(cO);
    __half h16 = __float2half(hO);
    S.hbuf[(tt + 1) & 1][chn] = h16;
    if (LAYER == 0) {
      hprev = h16;  // stored at top of next iteration
    } else {
      float av = hO > 0.f ? hO : 0.01f * hO;
      S.u.h1.abuf[tt & 1][chn] = __float2half(av);
    }
    xwc0 = __half2float(xn0); xwc1 = __half2float(xn1);
    xwc2 = __half2float(xn2); xwc3 = __half2float(xn3);

    STEP_BARRIER();  // lgkmcnt(0) + s_barrier only; no vmcnt drain

    // Head (layer1): 20 outputs x 8 lanes x 32 k; reads abuf[tt&1] written
    // before the barrier (next overwrite is 2 barriers away).
    if (LAYER == 1 && tid < OC * 8) {
      int o = tid >> 3, ks = tid & 7;
      const uint4* wp = (const uint4*)&S.u.h1.whd[o * 264 + ks * 32];
      const uint4* ap = (const uint4*)&S.u.h1.abuf[tt & 1][ks * 32];
      float a = 0.f;
#pragma unroll
      for (int q = 0; q < 4; q++) {
        uint4 w4 = wp[q];
        uint4 a4 = ap[q];
        a = fdot2(w4.x, a4.x, a);
        a = fdot2(w4.y, a4.y, a);
        a = fdot2(w4.z, a4.z, a);
        a = fdot2(w4.w, a4.w, a);
      }
      a += __shfl_xor(a, 1);
      a += __shfl_xor(a, 2);
      a += __shfl_xor(a, 4);
      if (ks == 0) P.y[(b * OC + o) * T_SEQ + t0 + tt] = a + S.u.h1.bh[o];
    }
  }
  if (LAYER == 0)
    P.h1w[(size_t)((Tc - 1) * NB + b) * 256 + chn] = hprev;
  hs[b * 256 + chn] = hO;
  cs[b * 256 + chn] = cO;
}

// ---------------------------------------------------------------------------
// GEMM role (VALU fdot2): xw1[tb,g] = sum_k h1[tb,k]*Wih1[g,k] + bs1[g].
// 128 blocks loop over 128-row strips (handles any Tc). A strip staged into
// S.w (stride-264, conflict-free); B via 16-way-broadcast global reads
// (wi1 is 512KB, L2-resident). tm=tid>>4 -> rows {tm+16r}, tn=tid&15 ->
// cols {np*64 + tn*4 + c}.
// ---------------------------------------------------------------------------
__device__ void role_gemm(SmemR& S, int chG, const Params& P) {
  if (chG < 0 || chG >= P.nch) return;
  const int nstrip = (P.Tc * NB) >> 7;
  const int tid = threadIdx.x;
  const int tm = tid >> 4, tn = tid & 15;
  for (int strip = blockIdx.x - 128; strip < nstrip; strip += 128) {
    const int tb0 = strip << 7;
    __syncthreads();
    for (int i = tid; i < 4096; i += THREADS) {
      int R = i >> 5, oct = i & 31;
      *(uint4*)&S.w[R * 264 + oct * 8] =
          *((const uint4*)(P.h1r + (size_t)(tb0 + R) * 256) + oct);
    }
    __syncthreads();
    for (int np = 0; np < 16; ++np) {
      const int g0 = np * 64 + tn * 4;
      float bs0v = P.bs1[g0],     bs1v = P.bs1[g0 + 1];
      float bs2v = P.bs1[g0 + 2], bs3v = P.bs1[g0 + 3];
      const __half* bp = P.wi1 + (size_t)g0 * 256;
      float acc[8][4] = {};
      for (int kq = 0; kq < 32; ++kq) {
        uint4 bv[4];
#pragma unroll
        for (int c = 0; c < 4; ++c)
          bv[c] = *(const uint4*)(bp + (size_t)c * 256 + kq * 8);
#pragma unroll
        for (int r = 0; r < 8; ++r) {
          uint4 av = *(const uint4*)&S.w[(tm + 16 * r) * 264 + kq * 8];
#pragma unroll
          for (int c = 0; c < 4; ++c) {
            float a = acc[r][c];
            a = fdot2(av.x, bv[c].x, a);
            a = fdot2(av.y, bv[c].y, a);
            a = fdot2(av.z, bv[c].z, a);
            a = fdot2(av.w, bv[c].w, a);
            acc[r][c] = a;
          }
        }
      }
#pragma unroll
      for (int r = 0; r < 8; ++r) {
        uint32_t* o =
            (uint32_t*)(P.xw1w + (size_t)(tb0 + tm + 16 * r) * G4 + g0);
        o[0] = pkh2(acc[r][0] + bs0v, acc[r][1] + bs1v);
        o[1] = pkh2(acc[r][2] + bs2v, acc[r][3] + bs3v);
      }
    }
  }
}

__global__ __launch_bounds__(THREADS)
__attribute__((amdgpu_waves_per_eu(1, 1)))
void fused_kernel(Params P) {
  __shared__ SmemR S;
  int bid = blockIdx.x;
  if (bid < 64)        role_rec<0>(S, P.L, P, bid);
  else if (bid < 128)  role_rec<1>(S, P.L - 2, P, bid - 64);
  else                 role_gemm(S, P.L - 1, P);
}

// ---------------------------------------------------------------------------
__global__ void prep_kernel(const float* Wih0, const float* Whh0,
                            const float* bih0, const float* bhh0,
                            const float* Wih1, const float* Whh1,
                            const float* bih1, const float* bhh1,
                            const float* Whead, const float* bhead,
                            __half* wh0, __half* wh1, __half* wi1, __half* wi0,
                            __half* whd, float* bs0, float* bs1, float* bhd) {
  int i = blockIdx.x * blockDim.x + threadIdx.x;
  if (i < G4 * HID) {
    wh0[i] = __float2half(Whh0[i]);
    wh1[i] = __float2half(Whh1[i]);
    wi1[i] = __float2half(Wih1[i]);
  }
  if (i < G4 * INCH) wi0[i] = __float2half(Wih0[i]);
  if (i < OC * HID)  whd[i] = __float2half(Whead[i]);
  if (i < G4) { bs0[i] = bih0[i] + bhh0[i]; bs1[i] = bih1[i] + bhh1[i]; }
  if (i < OC) bhd[i] = bhead[i];
}

// ---------------------------------------------------------------------------
extern "C" void kernel_launch(void* const* d_in, const int* in_sizes, int n_in,
                              void* d_out, int out_size, void* d_ws, size_t ws_size,
                              hipStream_t stream) {
  const float* x     = (const float*)d_in[0];
  const float* Wih0  = (const float*)d_in[1];
  const float* Whh0  = (const float*)d_in[2];
  const float* bih0  = (const float*)d_in[3];
  const float* bhh0  = (const float*)d_in[4];
  const float* Wih1  = (const float*)d_in[5];
  const float* Whh1  = (const float*)d_in[6];
  const float* bih1  = (const float*)d_in[7];
  const float* bhh1  = (const float*)d_in[8];
  const float* Whead = (const float*)d_in[9];
  const float* bhead = (const float*)d_in[10];
  float* y = (float*)d_out;

  char* ws = (char*)d_ws;
  size_t cur = 0;
  auto alloc = [&](size_t sz) -> char* {
    char* p = ws + cur;
    cur = (cur + sz + 255) & ~(size_t)255;
    return p;
  };
  __half* wh0 = (__half*)alloc(G4 * HID * 2);
  __half* wh1 = (__half*)alloc(G4 * HID * 2);
  __half* wi1 = (__half*)alloc(G4 * HID * 2);
  __half* wi0 = (__half*)alloc(G4 * INCH * 2);
  __half* whd = (__half*)alloc(OC * HID * 2);
  float* bs0 = (float*)alloc(G4 * 4);
  float* bs1 = (float*)alloc(G4 * 4);
  float* bhd = (float*)alloc(OC * 4);
  float* h0s = (float*)alloc(NB * HID * 4);
  float* c0s = (float*)alloc(NB * HID * 4);
  float* h1s = (float*)alloc(NB * HID * 4);
  float* c1s = (float*)alloc(NB * HID * 4);
  size_t fixed = cur;

  int Tc = 512;
  while (Tc > 64) {
    size_t need = fixed + 2 * ((size_t)Tc * NB * HID * 2 + 512) +
                  4 * ((size_t)Tc * NB * G4 * 2 + 512);
    if (need <= ws_size) break;
    Tc >>= 1;
  }
  __half* h1buf[2];
  __half* xw1buf[2];
  __half* xw0buf[2];
  h1buf[0]  = (__half*)alloc((size_t)Tc * NB * HID * 2);
  h1buf[1]  = (__half*)alloc((size_t)Tc * NB * HID * 2);
  xw1buf[0] = (__half*)alloc((size_t)Tc * NB * G4 * 2);
  xw1buf[1] = (__half*)alloc((size_t)Tc * NB * G4 * 2);
  xw0buf[0] = (__half*)alloc((size_t)Tc * NB * G4 * 2);
  xw0buf[1] = (__half*)alloc((size_t)Tc * NB * G4 * 2);

  const int nch = T_SEQ / Tc;

  prep_kernel<<<(G4 * HID + 255) / 256, 256, 0, stream>>>(
      Wih0, Whh0, bih0, bhh0, Wih1, Whh1, bih1, bhh1, Whead, bhead,
      wh0, wh1, wi1, wi0, whd, bs0, bs1, bhd);

  for (int L = 0; L < nch + 2; ++L) {
    Params P;
    P.x = x;
    P.wh0 = wh0; P.wh1 = wh1; P.wi0 = wi0; P.wi1 = wi1; P.whd = whd;
    P.bs0 = bs0; P.bs1 = bs1; P.bhd = bhd;
    P.h0s = h0s; P.c0s = c0s; P.h1s = h1s; P.c1s = c1s;
    P.h1w = h1buf[L & 1];
    P.h1r = h1buf[(L + 1) & 1];
    P.xw1w = xw1buf[(L + 1) & 1];
    P.xw1r = xw1buf[L & 1];
    P.xw0w = xw0buf[(L + 1) & 1];
    P.xw0r = xw0buf[L & 1];
    P.y = y;
    P.L = L; P.Tc = Tc; P.nch = nch;
    fused_kernel<<<256, THREADS, 0, stream>>>(P);
  }
}